// Round 4
// baseline (643.154 us; speedup 1.0000x reference)
//
#include <hip/hip_runtime.h>
#include <hip/hip_bf16.h>
#include <stdint.h>

// Problem constants (from reference)
#define NNODES 50000
#define NEDGES 800000
#define CH     256     // H*D = 256 for both GAT layers
#define NCLS   64

typedef __attribute__((ext_vector_type(8))) short  short8;
typedef __attribute__((ext_vector_type(4))) float  floatx4;

__device__ __forceinline__ float bf2f(unsigned short u) {
    union { unsigned int i; float f; } v; v.i = ((unsigned int)u) << 16; return v.f;
}
__device__ __forceinline__ unsigned short f2bf(float f) {
    union { float f; unsigned int i; } v; v.f = f;
    unsigned int x = v.i;
    return (unsigned short)((x + 0x7fffu + ((x >> 16) & 1u)) >> 16);  // RNE
}

// ---------------- small utility kernels ----------------

__global__ void k_zero(int* __restrict__ p, int n) {
    int i = blockIdx.x * 256 + threadIdx.x;
    if (i < n) p[i] = 0;
}

// transpose f32 [R,C] -> bf16 [C,R]
__global__ void k_transpose_cvt(const float* __restrict__ src,
                                unsigned short* __restrict__ dst, int R, int C) {
    int i = blockIdx.x * 256 + threadIdx.x;
    if (i < R * C) {
        int r = i / C, c = i % C;
        dst[c * R + r] = f2bf(src[i]);
    }
}

__global__ void k_hist(const int* __restrict__ dst, int* __restrict__ deg) {
    int e = blockIdx.x * 256 + threadIdx.x;
    if (e < NEDGES) {
        int d = dst[e];
        if ((unsigned)d < NNODES) atomicAdd(&deg[d], 1);
    }
}

// inclusive block scan; part[b] = block total
__global__ void k_scan1(const int* __restrict__ in, int* __restrict__ out,
                        int* __restrict__ part, int n) {
    __shared__ int sm[256];
    int i = blockIdx.x * 256 + threadIdx.x;
    int v = (i < n) ? in[i] : 0;
    sm[threadIdx.x] = v;
    __syncthreads();
    for (int off = 1; off < 256; off <<= 1) {
        int t = (threadIdx.x >= (unsigned)off) ? sm[threadIdx.x - off] : 0;
        __syncthreads();
        sm[threadIdx.x] += t;
        __syncthreads();
    }
    if (i < n) out[i] = sm[threadIdx.x];
    if (threadIdx.x == 255) part[blockIdx.x] = sm[255];
}

__global__ void k_scan3(const int* __restrict__ scn, const int* __restrict__ deg,
                        const int* __restrict__ part, int* __restrict__ offs,
                        int* __restrict__ cursor, int n) {
    int i = blockIdx.x * 256 + threadIdx.x;
    if (i < n) {
        int add = (blockIdx.x > 0) ? part[blockIdx.x - 1] : 0;
        int o = scn[i] - deg[i] + add;  // exclusive
        offs[i] = o; cursor[i] = o;
    }
}

__global__ void k_scatter(const int* __restrict__ dst, int* __restrict__ cursor,
                          int* __restrict__ eidx) {
    int e = blockIdx.x * 256 + threadIdx.x;
    if (e < NEDGES) {
        int d = dst[e];
        if ((unsigned)d < NNODES) {
            int p = atomicAdd(&cursor[d], 1);
            if ((unsigned)p < NEDGES) eidx[p] = e;
        }
    }
}

// ---------------- GEMM: C[M,BN] = A[M,256](f32) @ B (given BT[BN,256] bf16) ----------------
// A converted f32->bf16 during staging. Output f32 or bf16 per OUTF32.
// block: 256 thr = 4 waves; tile 128(M) x BN; wave -> 2 m-tiles x (BN/16) n-tiles.
template<int BN, bool OUTF32>
__global__ __launch_bounds__(256) void k_gemm(const float* __restrict__ A,
                                              const unsigned short* __restrict__ BT,
                                              const float* __restrict__ bias,   // f32[BN] or null
                                              float* __restrict__ Cf,
                                              unsigned short* __restrict__ Cb, int M) {
    constexpr int BK  = 32;
    constexpr int NT  = BN / 16;
    constexpr int LDA = BK + 8;            // pad: 80B row stride, 16B-aligned
    __shared__ unsigned short As[128][LDA];
    __shared__ unsigned short Bs[BN][LDA];
    const int t  = threadIdx.x;
    const int w  = t >> 6, l = t & 63;
    const int lm = l & 15, lk = (l >> 4) * 8;
    const int m0 = blockIdx.x * 128;

    floatx4 acc[2][NT];
#pragma unroll
    for (int mt = 0; mt < 2; ++mt)
#pragma unroll
        for (int nt = 0; nt < NT; ++nt) acc[mt][nt] = (floatx4)0.0f;

    for (int k0 = 0; k0 < 256; k0 += BK) {
        // stage A: 128 rows x 32 f32 -> bf16   (1024 float4 chunks)
#pragma unroll
        for (int p = 0; p < 4; ++p) {
            int chunk = t + p * 256;
            int r = chunk >> 3, cc = (chunk & 7) * 4;
            int row = m0 + r;
            float4 v = make_float4(0.f, 0.f, 0.f, 0.f);
            if (row < M) v = *(const float4*)(A + (size_t)row * 256 + k0 + cc);
            ushort4 o; o.x = f2bf(v.x); o.y = f2bf(v.y); o.z = f2bf(v.z); o.w = f2bf(v.w);
            *(ushort4*)&As[r][cc] = o;
        }
        // stage B: BN x 32 bf16
#pragma unroll
        for (int p = 0; p < (BN * 4) / 256; ++p) {
            int chunk = t + p * 256;
            int r = chunk >> 2, cc = (chunk & 3) * 8;
            *(uint4*)&Bs[r][cc] = *(const uint4*)(BT + (size_t)r * 256 + k0 + cc);
        }
        __syncthreads();
        short8 af0 = *(const short8*)&As[w * 32 +      lm][lk];
        short8 af1 = *(const short8*)&As[w * 32 + 16 + lm][lk];
#pragma unroll
        for (int nt = 0; nt < NT; ++nt) {
            short8 bf = *(const short8*)&Bs[nt * 16 + lm][lk];
            acc[0][nt] = __builtin_amdgcn_mfma_f32_16x16x32_bf16(af0, bf, acc[0][nt], 0, 0, 0);
            acc[1][nt] = __builtin_amdgcn_mfma_f32_16x16x32_bf16(af1, bf, acc[1][nt], 0, 0, 0);
        }
        __syncthreads();
    }
    // epilogue: D row=(lane>>4)*4+reg, col=lane&15 (m89 layout)
#pragma unroll
    for (int mt = 0; mt < 2; ++mt)
#pragma unroll
        for (int j = 0; j < 4; ++j) {
            int row = m0 + w * 32 + mt * 16 + (l >> 4) * 4 + j;
            if (row < M) {
#pragma unroll
                for (int nt = 0; nt < NT; ++nt) {
                    int col = nt * 16 + lm;
                    float v = acc[mt][nt][j];
                    if (bias) v += bias[col];
                    if (OUTF32) Cf[(size_t)row * BN + col] = v;
                    else        Cb[(size_t)row * BN + col] = f2bf(v);
                }
            }
        }
}

// ---------------- per-node attention logits el/er ----------------
template<int H>
__global__ void k_el_er(const unsigned short* __restrict__ ft,   // bf16 [N,CH]
                        const float* __restrict__ al,            // f32 [H*D]
                        const float* __restrict__ ar,
                        float* __restrict__ el, float* __restrict__ er) {
    constexpr int D = CH / H;      // 64 or 256
    constexpr int G = D / 4;       // lanes per head group (16 or 64)
    int n = blockIdx.x * 4 + (threadIdx.x >> 6);
    int l = threadIdx.x & 63;
    int c = 4 * l;
    int h = c / D;
    ushort4 f = *(const ushort4*)(ft + (size_t)n * CH + c);
    float4 a = *(const float4*)(al + c);
    float4 b = *(const float4*)(ar + c);
    float f0 = bf2f(f.x), f1 = bf2f(f.y), f2 = bf2f(f.z), f3 = bf2f(f.w);
    float sl = f0 * a.x + f1 * a.y + f2 * a.z + f3 * a.w;
    float sr = f0 * b.x + f1 * b.y + f2 * b.z + f3 * b.w;
#pragma unroll
    for (int m = 1; m < G; m <<= 1) {
        sl += __shfl_xor(sl, m, 64);
        sr += __shfl_xor(sr, m, 64);
    }
    if ((l & (G - 1)) == 0) {
        el[n * H + h] = sl;
        er[n * H + h] = sr;
    }
}

// ---------------- fused edge-softmax + aggregation (one wave per dst node) ----------------
// max-free softmax: acc += exp(e)*ft[src], s += exp(e); out = acc/s (+resid)(+bias)(elu?)
// All outputs f32.
template<int H, bool ELU>
__global__ void k_agg(const unsigned short* __restrict__ ft,     // bf16 [N,CH]
                      const float* __restrict__ el, const float* __restrict__ er,
                      const int* __restrict__ offs, const int* __restrict__ deg,
                      const int* __restrict__ eidx, const int* __restrict__ src,
                      const float* __restrict__ resid,           // f32 [N,CH] or null
                      const float* __restrict__ bias,            // f32 [CH]
                      float* __restrict__ out) {                 // f32 [N,CH]
    constexpr int D = CH / H;
    int n = blockIdx.x * 4 + (threadIdx.x >> 6);
    int l = threadIdx.x & 63;
    int c = 4 * l;
    int h = c / D;                 // all 4 channels of a lane share one head
    float ern = er[n * H + h];
    int st = offs[n], dg = deg[n];
    if (st < 0 || dg < 0 || st > NEDGES || dg > NEDGES - st) dg = 0;
    float a0 = 0.f, a1 = 0.f, a2 = 0.f, a3 = 0.f, ssum = 0.f;
    for (int i = 0; i < dg; ++i) {
        int e = eidx[st + i];
        if ((unsigned)e >= NEDGES) continue;
        int s = src[e];
        if ((unsigned)s >= NNODES) continue;
        float x = el[s * H + h] + ern;
        x = (x > 0.f) ? x : 0.2f * x;          // leaky_relu
        x = fminf(x, 60.f);                    // overflow guard (no-op on sane data)
        float wgt = __expf(x);
        ssum += wgt;
        ushort4 f = *(const ushort4*)(ft + (size_t)s * CH + c);
        a0 += wgt * bf2f(f.x); a1 += wgt * bf2f(f.y);
        a2 += wgt * bf2f(f.z); a3 += wgt * bf2f(f.w);
    }
    float inv = (ssum > 1e-30f) ? 1.0f / ssum : 0.0f;
    a0 *= inv; a1 *= inv; a2 *= inv; a3 *= inv;
    if (resid) {
        float4 r = *(const float4*)(resid + (size_t)n * CH + c);
        a0 += r.x; a1 += r.y; a2 += r.z; a3 += r.w;
    }
    {
        float4 b = *(const float4*)(bias + c);
        a0 += b.x; a1 += b.y; a2 += b.z; a3 += b.w;
    }
    if (ELU) {
        a0 = (a0 > 0.f) ? a0 : __expf(a0) - 1.f;
        a1 = (a1 > 0.f) ? a1 : __expf(a1) - 1.f;
        a2 = (a2 > 0.f) ? a2 : __expf(a2) - 1.f;
        a3 = (a3 > 0.f) ? a3 : __expf(a3) - 1.f;
    }
    *(float4*)(out + (size_t)n * CH + c) = make_float4(a0, a1, a2, a3);
}

// ---------------- launch ----------------

extern "C" void kernel_launch(void* const* d_in, const int* in_sizes, int n_in,
                              void* d_out, int out_size, void* d_ws, size_t ws_size,
                              hipStream_t stream) {
    const float* x   = (const float*)d_in[0];
    const int*   src = (const int*)d_in[1];
    const int*   dst = (const int*)d_in[2];
    const float* W0  = (const float*)d_in[3];
    const float* al0 = (const float*)d_in[4];
    const float* ar0 = (const float*)d_in[5];
    const float* b0  = (const float*)d_in[6];
    const float* W1  = (const float*)d_in[7];
    const float* al1 = (const float*)d_in[8];
    const float* ar1 = (const float*)d_in[9];
    const float* b1  = (const float*)d_in[10];
    const float* Wl  = (const float*)d_in[11];
    const float* bl  = (const float*)d_in[12];

    float* out_logits = (float*)d_out;                       // [50000*64]  12.8 MB
    float* out_h      = out_logits + (size_t)NNODES * NCLS;  // [50000*256] 51.2 MB

    // ---- scratch inside the logits region (12.8 MB; we use ~6.0 MB).
    // Consumed only before the final classifier GEMM, which overwrites it.
    char* ob = (char*)d_out;
    size_t oo = 0;
    auto oalloc = [&](size_t b) { char* p = ob + oo; oo += (b + 255) & ~(size_t)255; return p; };
    int*   eidx = (int*)oalloc((size_t)NEDGES * 4);          // 3.2 MB
    int*   deg  = (int*)oalloc((size_t)NNODES * 4);
    int*   offs = (int*)oalloc((size_t)NNODES * 4);
    int*   curs = (int*)oalloc((size_t)NNODES * 4);
    int*   scn  = (int*)oalloc((size_t)NNODES * 4);
    float* el0  = (float*)oalloc((size_t)NNODES * 4 * 4);
    float* er0  = (float*)oalloc((size_t)NNODES * 4 * 4);
    float* el1  = (float*)oalloc((size_t)NNODES * 4);
    float* er1  = (float*)oalloc((size_t)NNODES * 4);

    // ---- ws footprint: ~26 MB (ft bf16 + transposed bf16 weights)
    char* ws = (char*)d_ws;
    size_t o = 0;
    auto alloc = [&](size_t b) { char* p = ws + o; o += (b + 255) & ~(size_t)255; return p; };
    unsigned short* ft   = (unsigned short*)alloc((size_t)NNODES * CH * 2);  // 25.6 MB
    unsigned short* w0t  = (unsigned short*)alloc(256 * 256 * 2);
    unsigned short* w1t  = (unsigned short*)alloc(256 * 256 * 2);
    unsigned short* wlt  = (unsigned short*)alloc(64 * 256 * 2);
    int*            part = (int*)alloc(1024);
    int*            dmy  = (int*)alloc(256);

    // ---- weight transposes (f32 -> bf16) + CSR build ----
    k_zero<<<(NNODES + 255) / 256, 256, 0, stream>>>(deg, NNODES);
    k_transpose_cvt<<<(256 * 256 + 255) / 256, 256, 0, stream>>>(W0, w0t, 256, 256);
    k_transpose_cvt<<<(256 * 256 + 255) / 256, 256, 0, stream>>>(W1, w1t, 256, 256);
    k_transpose_cvt<<<(256 * 64 + 255) / 256, 256, 0, stream>>>(Wl, wlt, 256, 64);
    k_hist<<<(NEDGES + 255) / 256, 256, 0, stream>>>(dst, deg);
    int nb = (NNODES + 255) / 256;  // 196
    k_scan1<<<nb, 256, 0, stream>>>(deg, scn, part, NNODES);
    k_scan1<<<1, 256, 0, stream>>>(part, part, dmy, nb);
    k_scan3<<<nb, 256, 0, stream>>>(scn, deg, part, offs, curs, NNODES);
    k_scatter<<<(NEDGES + 255) / 256, 256, 0, stream>>>(dst, curs, eidx);

    int gm = (NNODES + 127) / 128;  // 391
    // ---- layer 0: ft0 = bf16(x @ W0); h0 -> out_h (f32) ----
    k_gemm<256, false><<<gm, 256, 0, stream>>>(x, w0t, nullptr, nullptr, ft, NNODES);
    k_el_er<4><<<NNODES / 4, 256, 0, stream>>>(ft, al0, ar0, el0, er0);
    k_agg<4, true><<<NNODES / 4, 256, 0, stream>>>(ft, el0, er0, offs, deg, eidx, src,
                                                   nullptr, b0, out_h);
    // ---- layer 1: ft1 = bf16(h0 @ W1); residual = h0 (in-place on out_h) ----
    k_gemm<256, false><<<gm, 256, 0, stream>>>(out_h, w1t, nullptr, nullptr, ft, NNODES);
    k_el_er<1><<<NNODES / 4, 256, 0, stream>>>(ft, al1, ar1, el1, er1);
    k_agg<1, false><<<NNODES / 4, 256, 0, stream>>>(ft, el1, er1, offs, deg, eidx, src,
                                                    out_h, b1, out_h);
    // ---- classifier: logits(f32) = h @ Wl + bl (overwrites scratch region last) ----
    k_gemm<64, true><<<gm, 256, 0, stream>>>(out_h, wlt, bl, out_logits, nullptr, NNODES);
}

// Round 5
// 481.477 us; speedup vs baseline: 1.3358x; 1.3358x over previous
//
#include <hip/hip_runtime.h>
#include <hip/hip_bf16.h>
#include <stdint.h>

// Problem constants (from reference)
#define NNODES 50000
#define NEDGES 800000
#define CH     256     // H*D = 256 for both GAT layers
#define NCLS   64

typedef __attribute__((ext_vector_type(8))) short  short8;
typedef __attribute__((ext_vector_type(4))) float  floatx4;

__device__ __forceinline__ float bf2f(unsigned short u) {
    union { unsigned int i; float f; } v; v.i = ((unsigned int)u) << 16; return v.f;
}
__device__ __forceinline__ unsigned short f2bf(float f) {
    union { float f; unsigned int i; } v; v.f = f;
    unsigned int x = v.i;
    return (unsigned short)((x + 0x7fffu + ((x >> 16) & 1u)) >> 16);  // RNE
}

// ---------------- fused setup: zero deg + transpose-convert all 3 weights ----------------
// idx ranges: [0,65536) W0 ; [65536,131072) W1 ; [131072,147456) Wl ; [147456,197456) deg=0
__global__ void k_setup(const float* __restrict__ W0, const float* __restrict__ W1,
                        const float* __restrict__ Wl,
                        unsigned short* __restrict__ w0t, unsigned short* __restrict__ w1t,
                        unsigned short* __restrict__ wlt, int* __restrict__ deg) {
    int i = blockIdx.x * 256 + threadIdx.x;
    if (i < 65536) {
        int r = i >> 8, c = i & 255;
        w0t[c * 256 + r] = f2bf(W0[i]);
    } else if (i < 131072) {
        int j = i - 65536;
        int r = j >> 8, c = j & 255;
        w1t[c * 256 + r] = f2bf(W1[j]);
    } else if (i < 147456) {
        int j = i - 131072;
        int r = j >> 6, c = j & 63;       // Wl is [256,64]
        wlt[c * 256 + r] = f2bf(Wl[j]);
    } else if (i < 147456 + NNODES) {
        deg[i - 147456] = 0;
    }
}

__global__ void k_hist(const int* __restrict__ dst, int* __restrict__ deg) {
    int e = blockIdx.x * 256 + threadIdx.x;
    if (e < NEDGES) {
        int d = dst[e];
        if ((unsigned)d < NNODES) atomicAdd(&deg[d], 1);
    }
}

// inclusive block scan; part[b] = block total
__global__ void k_scan1(const int* __restrict__ in, int* __restrict__ out,
                        int* __restrict__ part, int n) {
    __shared__ int sm[256];
    int i = blockIdx.x * 256 + threadIdx.x;
    int v = (i < n) ? in[i] : 0;
    sm[threadIdx.x] = v;
    __syncthreads();
    for (int off = 1; off < 256; off <<= 1) {
        int t = (threadIdx.x >= (unsigned)off) ? sm[threadIdx.x - off] : 0;
        __syncthreads();
        sm[threadIdx.x] += t;
        __syncthreads();
    }
    if (i < n) out[i] = sm[threadIdx.x];
    if (threadIdx.x == 255) part[blockIdx.x] = sm[255];
}

__global__ void k_scan3(const int* __restrict__ scn, const int* __restrict__ deg,
                        const int* __restrict__ part, int* __restrict__ offs,
                        int* __restrict__ cursor, int n) {
    int i = blockIdx.x * 256 + threadIdx.x;
    if (i < n) {
        int add = (blockIdx.x > 0) ? part[blockIdx.x - 1] : 0;
        int o = scn[i] - deg[i] + add;  // exclusive
        offs[i] = o; cursor[i] = o;
    }
}

// scatter: store SOURCE node id at CSR slot (removes one indirection in k_agg)
__global__ void k_scatter(const int* __restrict__ dst, const int* __restrict__ src,
                          int* __restrict__ cursor, int* __restrict__ esrc) {
    int e = blockIdx.x * 256 + threadIdx.x;
    if (e < NEDGES) {
        int d = dst[e];
        if ((unsigned)d < NNODES) {
            int p = atomicAdd(&cursor[d], 1);
            if ((unsigned)p < NEDGES) esrc[p] = src[e];
        }
    }
}

// ---------------- GEMM: C[M,BN] = A[M,256](f32) @ B (given BT[BN,256] bf16) ----------------
template<int BN, bool OUTF32>
__global__ __launch_bounds__(256) void k_gemm(const float* __restrict__ A,
                                              const unsigned short* __restrict__ BT,
                                              const float* __restrict__ bias,   // f32[BN] or null
                                              float* __restrict__ Cf,
                                              unsigned short* __restrict__ Cb, int M) {
    constexpr int BK  = 32;
    constexpr int NT  = BN / 16;
    constexpr int LDA = BK + 8;            // pad: 80B row stride, 16B-aligned
    __shared__ unsigned short As[128][LDA];
    __shared__ unsigned short Bs[BN][LDA];
    const int t  = threadIdx.x;
    const int w  = t >> 6, l = t & 63;
    const int lm = l & 15, lk = (l >> 4) * 8;
    const int m0 = blockIdx.x * 128;

    floatx4 acc[2][NT];
#pragma unroll
    for (int mt = 0; mt < 2; ++mt)
#pragma unroll
        for (int nt = 0; nt < NT; ++nt) acc[mt][nt] = (floatx4)0.0f;

    for (int k0 = 0; k0 < 256; k0 += BK) {
        // stage A: 128 rows x 32 f32 -> bf16
#pragma unroll
        for (int p = 0; p < 4; ++p) {
            int chunk = t + p * 256;
            int r = chunk >> 3, cc = (chunk & 7) * 4;
            int row = m0 + r;
            float4 v = make_float4(0.f, 0.f, 0.f, 0.f);
            if (row < M) v = *(const float4*)(A + (size_t)row * 256 + k0 + cc);
            ushort4 o; o.x = f2bf(v.x); o.y = f2bf(v.y); o.z = f2bf(v.z); o.w = f2bf(v.w);
            *(ushort4*)&As[r][cc] = o;
        }
        // stage B: BN x 32 bf16
#pragma unroll
        for (int p = 0; p < (BN * 4) / 256; ++p) {
            int chunk = t + p * 256;
            int r = chunk >> 2, cc = (chunk & 3) * 8;
            *(uint4*)&Bs[r][cc] = *(const uint4*)(BT + (size_t)r * 256 + k0 + cc);
        }
        __syncthreads();
        short8 af0 = *(const short8*)&As[w * 32 +      lm][lk];
        short8 af1 = *(const short8*)&As[w * 32 + 16 + lm][lk];
#pragma unroll
        for (int nt = 0; nt < NT; ++nt) {
            short8 bf = *(const short8*)&Bs[nt * 16 + lm][lk];
            acc[0][nt] = __builtin_amdgcn_mfma_f32_16x16x32_bf16(af0, bf, acc[0][nt], 0, 0, 0);
            acc[1][nt] = __builtin_amdgcn_mfma_f32_16x16x32_bf16(af1, bf, acc[1][nt], 0, 0, 0);
        }
        __syncthreads();
    }
    // epilogue: D row=(lane>>4)*4+reg, col=lane&15 (m89 layout)
#pragma unroll
    for (int mt = 0; mt < 2; ++mt)
#pragma unroll
        for (int j = 0; j < 4; ++j) {
            int row = m0 + w * 32 + mt * 16 + (l >> 4) * 4 + j;
            if (row < M) {
#pragma unroll
                for (int nt = 0; nt < NT; ++nt) {
                    int col = nt * 16 + lm;
                    float v = acc[mt][nt][j];
                    if (bias) v += bias[col];
                    if (OUTF32) Cf[(size_t)row * BN + col] = v;
                    else        Cb[(size_t)row * BN + col] = f2bf(v);
                }
            }
        }
}

// ---------------- per-node attention logits el/er ----------------
template<int H>
__global__ void k_el_er(const unsigned short* __restrict__ ft,   // bf16 [N,CH]
                        const float* __restrict__ al,            // f32 [H*D]
                        const float* __restrict__ ar,
                        float* __restrict__ el, float* __restrict__ er) {
    constexpr int D = CH / H;      // 64 or 256
    constexpr int G = D / 4;       // lanes per head group (16 or 64)
    int n = blockIdx.x * 4 + (threadIdx.x >> 6);
    int l = threadIdx.x & 63;
    int c = 4 * l;
    int h = c / D;
    ushort4 f = *(const ushort4*)(ft + (size_t)n * CH + c);
    float4 a = *(const float4*)(al + c);
    float4 b = *(const float4*)(ar + c);
    float f0 = bf2f(f.x), f1 = bf2f(f.y), f2 = bf2f(f.z), f3 = bf2f(f.w);
    float sl = f0 * a.x + f1 * a.y + f2 * a.z + f3 * a.w;
    float sr = f0 * b.x + f1 * b.y + f2 * b.z + f3 * b.w;
#pragma unroll
    for (int m = 1; m < G; m <<= 1) {
        sl += __shfl_xor(sl, m, 64);
        sr += __shfl_xor(sr, m, 64);
    }
    if ((l & (G - 1)) == 0) {
        el[n * H + h] = sl;
        er[n * H + h] = sr;
    }
}

// ---------------- fused edge-softmax + aggregation (one wave per dst node) ----------------
// max-free softmax, unrolled x4 so 4 independent gather chains are in flight.
template<int H, bool ELU>
__global__ void k_agg(const unsigned short* __restrict__ ft,     // bf16 [N,CH]
                      const float* __restrict__ el, const float* __restrict__ er,
                      const int* __restrict__ offs, const int* __restrict__ deg,
                      const int* __restrict__ esrc,               // CSR: src node ids
                      const float* __restrict__ resid,            // f32 [N,CH] or null
                      const float* __restrict__ bias,             // f32 [CH]
                      float* __restrict__ out) {                  // f32 [N,CH]
    constexpr int D = CH / H;
    int n = blockIdx.x * 4 + (threadIdx.x >> 6);
    int l = threadIdx.x & 63;
    int c = 4 * l;
    int h = c / D;                 // all 4 channels of a lane share one head
    float ern = er[n * H + h];
    int st = offs[n], dg = deg[n];
    if (st < 0 || dg < 0 || st > NEDGES || dg > NEDGES - st) dg = 0;
    float a0 = 0.f, a1 = 0.f, a2 = 0.f, a3 = 0.f, ssum = 0.f;
    int i = 0;
    for (; i + 4 <= dg; i += 4) {
        // all loads independent -> 4 gather chains in flight
        int s0 = esrc[st + i],     s1 = esrc[st + i + 1];
        int s2 = esrc[st + i + 2], s3 = esrc[st + i + 3];
        float x0 = el[s0 * H + h], x1 = el[s1 * H + h];
        float x2 = el[s2 * H + h], x3 = el[s3 * H + h];
        ushort4 f0 = *(const ushort4*)(ft + (size_t)s0 * CH + c);
        ushort4 f1 = *(const ushort4*)(ft + (size_t)s1 * CH + c);
        ushort4 f2 = *(const ushort4*)(ft + (size_t)s2 * CH + c);
        ushort4 f3 = *(const ushort4*)(ft + (size_t)s3 * CH + c);
        x0 += ern; x0 = (x0 > 0.f) ? x0 : 0.2f * x0; x0 = fminf(x0, 60.f);
        x1 += ern; x1 = (x1 > 0.f) ? x1 : 0.2f * x1; x1 = fminf(x1, 60.f);
        x2 += ern; x2 = (x2 > 0.f) ? x2 : 0.2f * x2; x2 = fminf(x2, 60.f);
        x3 += ern; x3 = (x3 > 0.f) ? x3 : 0.2f * x3; x3 = fminf(x3, 60.f);
        float w0 = __expf(x0), w1 = __expf(x1), w2 = __expf(x2), w3 = __expf(x3);
        ssum += (w0 + w1) + (w2 + w3);
        a0 += w0 * bf2f(f0.x) + w1 * bf2f(f1.x) + w2 * bf2f(f2.x) + w3 * bf2f(f3.x);
        a1 += w0 * bf2f(f0.y) + w1 * bf2f(f1.y) + w2 * bf2f(f2.y) + w3 * bf2f(f3.y);
        a2 += w0 * bf2f(f0.z) + w1 * bf2f(f1.z) + w2 * bf2f(f2.z) + w3 * bf2f(f3.z);
        a3 += w0 * bf2f(f0.w) + w1 * bf2f(f1.w) + w2 * bf2f(f2.w) + w3 * bf2f(f3.w);
    }
    for (; i < dg; ++i) {
        int s = esrc[st + i];
        float x = el[s * H + h] + ern;
        x = (x > 0.f) ? x : 0.2f * x;
        x = fminf(x, 60.f);
        float wgt = __expf(x);
        ssum += wgt;
        ushort4 f = *(const ushort4*)(ft + (size_t)s * CH + c);
        a0 += wgt * bf2f(f.x); a1 += wgt * bf2f(f.y);
        a2 += wgt * bf2f(f.z); a3 += wgt * bf2f(f.w);
    }
    float inv = (ssum > 1e-30f) ? 1.0f / ssum : 0.0f;
    a0 *= inv; a1 *= inv; a2 *= inv; a3 *= inv;
    if (resid) {
        float4 r = *(const float4*)(resid + (size_t)n * CH + c);
        a0 += r.x; a1 += r.y; a2 += r.z; a3 += r.w;
    }
    {
        float4 b = *(const float4*)(bias + c);
        a0 += b.x; a1 += b.y; a2 += b.z; a3 += b.w;
    }
    if (ELU) {
        a0 = (a0 > 0.f) ? a0 : __expf(a0) - 1.f;
        a1 = (a1 > 0.f) ? a1 : __expf(a1) - 1.f;
        a2 = (a2 > 0.f) ? a2 : __expf(a2) - 1.f;
        a3 = (a3 > 0.f) ? a3 : __expf(a3) - 1.f;
    }
    *(float4*)(out + (size_t)n * CH + c) = make_float4(a0, a1, a2, a3);
}

// ---------------- launch ----------------

extern "C" void kernel_launch(void* const* d_in, const int* in_sizes, int n_in,
                              void* d_out, int out_size, void* d_ws, size_t ws_size,
                              hipStream_t stream) {
    const float* x   = (const float*)d_in[0];
    const int*   src = (const int*)d_in[1];
    const int*   dst = (const int*)d_in[2];
    const float* W0  = (const float*)d_in[3];
    const float* al0 = (const float*)d_in[4];
    const float* ar0 = (const float*)d_in[5];
    const float* b0  = (const float*)d_in[6];
    const float* W1  = (const float*)d_in[7];
    const float* al1 = (const float*)d_in[8];
    const float* ar1 = (const float*)d_in[9];
    const float* b1  = (const float*)d_in[10];
    const float* Wl  = (const float*)d_in[11];
    const float* bl  = (const float*)d_in[12];

    float* out_logits = (float*)d_out;                       // [50000*64]  12.8 MB
    float* out_h      = out_logits + (size_t)NNODES * NCLS;  // [50000*256] 51.2 MB

    // ---- scratch inside the logits region (12.8 MB; we use ~6.0 MB).
    char* ob = (char*)d_out;
    size_t oo = 0;
    auto oalloc = [&](size_t b) { char* p = ob + oo; oo += (b + 255) & ~(size_t)255; return p; };
    int*   esrc = (int*)oalloc((size_t)NEDGES * 4);          // 3.2 MB (CSR src ids)
    int*   deg  = (int*)oalloc((size_t)NNODES * 4);
    int*   offs = (int*)oalloc((size_t)NNODES * 4);
    int*   curs = (int*)oalloc((size_t)NNODES * 4);
    int*   scn  = (int*)oalloc((size_t)NNODES * 4);
    float* el0  = (float*)oalloc((size_t)NNODES * 4 * 4);
    float* er0  = (float*)oalloc((size_t)NNODES * 4 * 4);
    float* el1  = (float*)oalloc((size_t)NNODES * 4);
    float* er1  = (float*)oalloc((size_t)NNODES * 4);

    // ---- ws footprint: ~26 MB (ft bf16 + transposed bf16 weights)
    char* ws = (char*)d_ws;
    size_t o = 0;
    auto alloc = [&](size_t b) { char* p = ws + o; o += (b + 255) & ~(size_t)255; return p; };
    unsigned short* ft   = (unsigned short*)alloc((size_t)NNODES * CH * 2);  // 25.6 MB
    unsigned short* w0t  = (unsigned short*)alloc(256 * 256 * 2);
    unsigned short* w1t  = (unsigned short*)alloc(256 * 256 * 2);
    unsigned short* wlt  = (unsigned short*)alloc(64 * 256 * 2);
    int*            part = (int*)alloc(1024);
    int*            dmy  = (int*)alloc(256);

    // ---- setup (weight transposes + deg=0) + CSR build ----
    k_setup<<<(147456 + NNODES + 255) / 256, 256, 0, stream>>>(W0, W1, Wl, w0t, w1t, wlt, deg);
    k_hist<<<(NEDGES + 255) / 256, 256, 0, stream>>>(dst, deg);
    int nb = (NNODES + 255) / 256;  // 196
    k_scan1<<<nb, 256, 0, stream>>>(deg, scn, part, NNODES);
    k_scan1<<<1, 256, 0, stream>>>(part, part, dmy, nb);
    k_scan3<<<nb, 256, 0, stream>>>(scn, deg, part, offs, curs, NNODES);
    k_scatter<<<(NEDGES + 255) / 256, 256, 0, stream>>>(dst, src, curs, esrc);

    int gm = (NNODES + 127) / 128;  // 391
    // ---- layer 0: ft0 = bf16(x @ W0); h0 -> out_h (f32) ----
    k_gemm<256, false><<<gm, 256, 0, stream>>>(x, w0t, nullptr, nullptr, ft, NNODES);
    k_el_er<4><<<NNODES / 4, 256, 0, stream>>>(ft, al0, ar0, el0, er0);
    k_agg<4, true><<<NNODES / 4, 256, 0, stream>>>(ft, el0, er0, offs, deg, esrc,
                                                   nullptr, b0, out_h);
    // ---- layer 1: ft1 = bf16(h0 @ W1); residual = h0 (in-place on out_h) ----
    k_gemm<256, false><<<gm, 256, 0, stream>>>(out_h, w1t, nullptr, nullptr, ft, NNODES);
    k_el_er<1><<<NNODES / 4, 256, 0, stream>>>(ft, al1, ar1, el1, er1);
    k_agg<1, false><<<NNODES / 4, 256, 0, stream>>>(ft, el1, er1, offs, deg, esrc,
                                                    out_h, b1, out_h);
    // ---- classifier: logits(f32) = h @ Wl + bl (overwrites scratch region last) ----
    k_gemm<64, true><<<gm, 256, 0, stream>>>(out_h, wlt, bl, out_logits, nullptr, NNODES);
}

// Round 6
// 432.269 us; speedup vs baseline: 1.4879x; 1.1138x over previous
//
#include <hip/hip_runtime.h>
#include <hip/hip_bf16.h>
#include <stdint.h>

#define NNODES 50000
#define NEDGES 800000
#define CH     256
#define NCLS   64

typedef __attribute__((ext_vector_type(8))) short  short8;
typedef __attribute__((ext_vector_type(4))) float  floatx4;

__device__ __forceinline__ float bf2f(unsigned short u) {
    union { unsigned int i; float f; } v; v.i = ((unsigned int)u) << 16; return v.f;
}
__device__ __forceinline__ unsigned short f2bf(float f) {
    union { float f; unsigned int i; } v; v.f = f;
    unsigned int x = v.i;
    return (unsigned short)((x + 0x7fffu + ((x >> 16) & 1u)) >> 16);  // RNE
}

// ---------------- fused setup: zero deg + transpose-convert all 3 weights ----------------
__global__ void k_setup(const float* __restrict__ W0, const float* __restrict__ W1,
                        const float* __restrict__ Wl,
                        unsigned short* __restrict__ w0t, unsigned short* __restrict__ w1t,
                        unsigned short* __restrict__ wlt, int* __restrict__ deg) {
    int i = blockIdx.x * 256 + threadIdx.x;
    if (i < 65536) {
        int r = i >> 8, c = i & 255;
        w0t[c * 256 + r] = f2bf(W0[i]);
    } else if (i < 131072) {
        int j = i - 65536;
        int r = j >> 8, c = j & 255;
        w1t[c * 256 + r] = f2bf(W1[j]);
    } else if (i < 147456) {
        int j = i - 131072;
        int r = j >> 6, c = j & 63;       // Wl is [256,64]
        wlt[c * 256 + r] = f2bf(Wl[j]);
    } else if (i < 147456 + NNODES) {
        deg[i - 147456] = 0;
    }
}

__global__ void k_hist(const int* __restrict__ dst, int* __restrict__ deg) {
    int e = blockIdx.x * 256 + threadIdx.x;
    if (e < NEDGES) {
        int d = dst[e];
        if ((unsigned)d < NNODES) atomicAdd(&deg[d], 1);
    }
}

__global__ void k_scan1(const int* __restrict__ in, int* __restrict__ out,
                        int* __restrict__ part, int n) {
    __shared__ int sm[256];
    int i = blockIdx.x * 256 + threadIdx.x;
    int v = (i < n) ? in[i] : 0;
    sm[threadIdx.x] = v;
    __syncthreads();
    for (int off = 1; off < 256; off <<= 1) {
        int t = (threadIdx.x >= (unsigned)off) ? sm[threadIdx.x - off] : 0;
        __syncthreads();
        sm[threadIdx.x] += t;
        __syncthreads();
    }
    if (i < n) out[i] = sm[threadIdx.x];
    if (threadIdx.x == 255) part[blockIdx.x] = sm[255];
}

__global__ void k_scan3(const int* __restrict__ scn, const int* __restrict__ deg,
                        const int* __restrict__ part, int* __restrict__ offs,
                        int* __restrict__ cursor, int n) {
    int i = blockIdx.x * 256 + threadIdx.x;
    if (i < n) {
        int add = (blockIdx.x > 0) ? part[blockIdx.x - 1] : 0;
        int o = scn[i] - deg[i] + add;
        offs[i] = o; cursor[i] = o;
    }
}

__global__ void k_scatter(const int* __restrict__ dst, const int* __restrict__ src,
                          int* __restrict__ cursor, int* __restrict__ esrc) {
    int e = blockIdx.x * 256 + threadIdx.x;
    if (e < NEDGES) {
        int d = dst[e];
        if ((unsigned)d < NNODES) {
            int p = atomicAdd(&cursor[d], 1);
            if ((unsigned)p < NEDGES) esrc[p] = src[e];
        }
    }
}

// ---------------- GEMM: C[M, N] tile 128(M) x BN(N); A[M,256] f32 or bf16 ----------------
// grid: (ceil(M/128), N/BN). 256 thr = 4 waves; wave -> 2 m-tiles x (BN/16) n-tiles.
template<int BN, bool ABF16, bool OUTF32>
__global__ __launch_bounds__(256) void k_gemm(const void* __restrict__ Av,
                                              const unsigned short* __restrict__ BT,
                                              const float* __restrict__ bias,
                                              float* __restrict__ Cf,
                                              unsigned short* __restrict__ Cb,
                                              int M, int N) {
    constexpr int BK  = 32;
    constexpr int NT  = BN / 16;
    constexpr int LDA = BK + 8;            // 80 B row stride
    __shared__ unsigned short As[128][LDA];
    __shared__ unsigned short Bs[BN][LDA];
    const int t  = threadIdx.x;
    const int w  = t >> 6, l = t & 63;
    const int lm = l & 15, lk = (l >> 4) * 8;
    const int m0 = blockIdx.x * 128;
    const int n0 = blockIdx.y * BN;
    const float* Af = (const float*)Av;
    const unsigned short* Ab = (const unsigned short*)Av;

    floatx4 acc[2][NT];
#pragma unroll
    for (int mt = 0; mt < 2; ++mt)
#pragma unroll
        for (int nt = 0; nt < NT; ++nt) acc[mt][nt] = (floatx4)0.0f;

    for (int k0 = 0; k0 < 256; k0 += BK) {
        if (ABF16) {
            // stage A: 128x32 bf16, 512 chunks of 8 elems (16 B)
#pragma unroll
            for (int p = 0; p < 2; ++p) {
                int chunk = t + p * 256;
                int r = chunk >> 2, cc = (chunk & 3) * 8;
                int row = m0 + r;
                uint4 val = make_uint4(0, 0, 0, 0);
                if (row < M) val = *(const uint4*)(Ab + (size_t)row * 256 + k0 + cc);
                *(uint4*)&As[r][cc] = val;
            }
        } else {
            // stage A: 128x32 f32 -> bf16, 1024 chunks of 4 elems
#pragma unroll
            for (int p = 0; p < 4; ++p) {
                int chunk = t + p * 256;
                int r = chunk >> 3, cc = (chunk & 7) * 4;
                int row = m0 + r;
                float4 v = make_float4(0.f, 0.f, 0.f, 0.f);
                if (row < M) v = *(const float4*)(Af + (size_t)row * 256 + k0 + cc);
                ushort4 o; o.x = f2bf(v.x); o.y = f2bf(v.y); o.z = f2bf(v.z); o.w = f2bf(v.w);
                *(ushort4*)&As[r][cc] = o;
            }
        }
        // stage B: BN x 32 bf16
#pragma unroll
        for (int p = 0; p < (BN * 4) / 256; ++p) {
            int chunk = t + p * 256;
            int r = chunk >> 2, cc = (chunk & 3) * 8;
            *(uint4*)&Bs[r][cc] = *(const uint4*)(BT + (size_t)(n0 + r) * 256 + k0 + cc);
        }
        __syncthreads();
        short8 af0 = *(const short8*)&As[w * 32 +      lm][lk];
        short8 af1 = *(const short8*)&As[w * 32 + 16 + lm][lk];
#pragma unroll
        for (int nt = 0; nt < NT; ++nt) {
            short8 bf = *(const short8*)&Bs[nt * 16 + lm][lk];
            acc[0][nt] = __builtin_amdgcn_mfma_f32_16x16x32_bf16(af0, bf, acc[0][nt], 0, 0, 0);
            acc[1][nt] = __builtin_amdgcn_mfma_f32_16x16x32_bf16(af1, bf, acc[1][nt], 0, 0, 0);
        }
        __syncthreads();
    }
    // epilogue: D row=(lane>>4)*4+reg, col=lane&15
#pragma unroll
    for (int mt = 0; mt < 2; ++mt)
#pragma unroll
        for (int j = 0; j < 4; ++j) {
            int row = m0 + w * 32 + mt * 16 + (l >> 4) * 4 + j;
            if (row < M) {
#pragma unroll
                for (int nt = 0; nt < NT; ++nt) {
                    int gcol = n0 + nt * 16 + lm;
                    float v = acc[mt][nt][j];
                    if (bias) v += bias[gcol];
                    if (OUTF32) Cf[(size_t)row * N + gcol] = v;
                    else        Cb[(size_t)row * N + gcol] = f2bf(v);
                }
            }
        }
}

// ---------------- per-node attention logits el/er ----------------
template<int H>
__global__ void k_el_er(const unsigned short* __restrict__ ft,
                        const float* __restrict__ al, const float* __restrict__ ar,
                        float* __restrict__ el, float* __restrict__ er) {
    constexpr int D = CH / H;
    constexpr int G = D / 4;
    int n = blockIdx.x * 4 + (threadIdx.x >> 6);
    int l = threadIdx.x & 63;
    int c = 4 * l;
    int h = c / D;
    ushort4 f = *(const ushort4*)(ft + (size_t)n * CH + c);
    float4 a = *(const float4*)(al + c);
    float4 b = *(const float4*)(ar + c);
    float f0 = bf2f(f.x), f1 = bf2f(f.y), f2 = bf2f(f.z), f3 = bf2f(f.w);
    float sl = f0 * a.x + f1 * a.y + f2 * a.z + f3 * a.w;
    float sr = f0 * b.x + f1 * b.y + f2 * b.z + f3 * b.w;
#pragma unroll
    for (int m = 1; m < G; m <<= 1) {
        sl += __shfl_xor(sl, m, 64);
        sr += __shfl_xor(sr, m, 64);
    }
    if ((l & (G - 1)) == 0) {
        el[n * H + h] = sl;
        er[n * H + h] = sr;
    }
}

// ---------------- fused edge-softmax + aggregation (one wave per dst node) ----------------
// unrolled x8 -> 8 independent gather chains in flight per wave.
template<int H, bool ELU, bool RESID>
__global__ void k_agg(const unsigned short* __restrict__ ft,
                      const float* __restrict__ el, const float* __restrict__ er,
                      const int* __restrict__ offs, const int* __restrict__ deg,
                      const int* __restrict__ esrc,
                      const unsigned short* __restrict__ resid16,   // bf16 or null
                      const float* __restrict__ bias,
                      unsigned short* __restrict__ out_bf,          // bf16 out (or null)
                      float* __restrict__ out_f) {                  // f32 out (or null)
    constexpr int D = CH / H;
    int n = blockIdx.x * 4 + (threadIdx.x >> 6);
    int l = threadIdx.x & 63;
    int c = 4 * l;
    int h = c / D;
    float ern = er[n * H + h];
    int st = offs[n], dg = deg[n];
    if (st < 0 || dg < 0 || st > NEDGES || dg > NEDGES - st) dg = 0;
    float a0 = 0.f, a1 = 0.f, a2 = 0.f, a3 = 0.f, ssum = 0.f;
    int i = 0;
    for (; i + 8 <= dg; i += 8) {
        int s[8];
#pragma unroll
        for (int u = 0; u < 8; ++u) s[u] = esrc[st + i + u];
        float x[8];
#pragma unroll
        for (int u = 0; u < 8; ++u) x[u] = el[s[u] * H + h];
        ushort4 f[8];
#pragma unroll
        for (int u = 0; u < 8; ++u) f[u] = *(const ushort4*)(ft + (size_t)s[u] * CH + c);
#pragma unroll
        for (int u = 0; u < 8; ++u) {
            float xv = x[u] + ern;
            xv = (xv > 0.f) ? xv : 0.2f * xv;
            xv = fminf(xv, 60.f);
            float wgt = __expf(xv);
            ssum += wgt;
            a0 += wgt * bf2f(f[u].x); a1 += wgt * bf2f(f[u].y);
            a2 += wgt * bf2f(f[u].z); a3 += wgt * bf2f(f[u].w);
        }
    }
    for (; i < dg; ++i) {
        int s = esrc[st + i];
        float xv = el[s * H + h] + ern;
        xv = (xv > 0.f) ? xv : 0.2f * xv;
        xv = fminf(xv, 60.f);
        float wgt = __expf(xv);
        ssum += wgt;
        ushort4 f = *(const ushort4*)(ft + (size_t)s * CH + c);
        a0 += wgt * bf2f(f.x); a1 += wgt * bf2f(f.y);
        a2 += wgt * bf2f(f.z); a3 += wgt * bf2f(f.w);
    }
    float inv = (ssum > 1e-30f) ? 1.0f / ssum : 0.0f;
    a0 *= inv; a1 *= inv; a2 *= inv; a3 *= inv;
    if (RESID) {
        ushort4 r = *(const ushort4*)(resid16 + (size_t)n * CH + c);
        a0 += bf2f(r.x); a1 += bf2f(r.y); a2 += bf2f(r.z); a3 += bf2f(r.w);
    }
    {
        float4 b = *(const float4*)(bias + c);
        a0 += b.x; a1 += b.y; a2 += b.z; a3 += b.w;
    }
    if (ELU) {
        a0 = (a0 > 0.f) ? a0 : __expf(a0) - 1.f;
        a1 = (a1 > 0.f) ? a1 : __expf(a1) - 1.f;
        a2 = (a2 > 0.f) ? a2 : __expf(a2) - 1.f;
        a3 = (a3 > 0.f) ? a3 : __expf(a3) - 1.f;
    }
    if (out_bf) {
        ushort4 ov; ov.x = f2bf(a0); ov.y = f2bf(a1); ov.z = f2bf(a2); ov.w = f2bf(a3);
        *(ushort4*)(out_bf + (size_t)n * CH + c) = ov;
    }
    if (out_f) {
        *(float4*)(out_f + (size_t)n * CH + c) = make_float4(a0, a1, a2, a3);
    }
}

// ---------------- launch ----------------

extern "C" void kernel_launch(void* const* d_in, const int* in_sizes, int n_in,
                              void* d_out, int out_size, void* d_ws, size_t ws_size,
                              hipStream_t stream) {
    const float* x   = (const float*)d_in[0];
    const int*   src = (const int*)d_in[1];
    const int*   dst = (const int*)d_in[2];
    const float* W0  = (const float*)d_in[3];
    const float* al0 = (const float*)d_in[4];
    const float* ar0 = (const float*)d_in[5];
    const float* b0  = (const float*)d_in[6];
    const float* W1  = (const float*)d_in[7];
    const float* al1 = (const float*)d_in[8];
    const float* ar1 = (const float*)d_in[9];
    const float* b1  = (const float*)d_in[10];
    const float* Wl  = (const float*)d_in[11];
    const float* bl  = (const float*)d_in[12];

    float* out_logits = (float*)d_out;                       // [50000*64]
    float* out_h      = out_logits + (size_t)NNODES * NCLS;  // [50000*256]

    // scratch in the logits region (12.8 MB; we use ~6.0 MB), overwritten last
    char* ob = (char*)d_out;
    size_t oo = 0;
    auto oalloc = [&](size_t b) { char* p = ob + oo; oo += (b + 255) & ~(size_t)255; return p; };
    int*   esrc = (int*)oalloc((size_t)NEDGES * 4);
    int*   deg  = (int*)oalloc((size_t)NNODES * 4);
    int*   offs = (int*)oalloc((size_t)NNODES * 4);
    int*   curs = (int*)oalloc((size_t)NNODES * 4);
    int*   scn  = (int*)oalloc((size_t)NNODES * 4);
    float* el0  = (float*)oalloc((size_t)NNODES * 4 * 4);
    float* er0  = (float*)oalloc((size_t)NNODES * 4 * 4);
    float* el1  = (float*)oalloc((size_t)NNODES * 4);
    float* er1  = (float*)oalloc((size_t)NNODES * 4);

    // ws: ft (25.6) + h0bf (25.6) + weights (~0.3) ≈ 51.6 MB
    char* ws = (char*)d_ws;
    size_t o = 0;
    auto alloc = [&](size_t b) { char* p = ws + o; o += (b + 255) & ~(size_t)255; return p; };
    unsigned short* ft   = (unsigned short*)alloc((size_t)NNODES * CH * 2);
    unsigned short* h0bf = (unsigned short*)alloc((size_t)NNODES * CH * 2);
    unsigned short* w0t  = (unsigned short*)alloc(256 * 256 * 2);
    unsigned short* w1t  = (unsigned short*)alloc(256 * 256 * 2);
    unsigned short* wlt  = (unsigned short*)alloc(64 * 256 * 2);
    int*            part = (int*)alloc(1024);
    int*            dmy  = (int*)alloc(256);

    // ---- setup + CSR build ----
    k_setup<<<(147456 + NNODES + 255) / 256, 256, 0, stream>>>(W0, W1, Wl, w0t, w1t, wlt, deg);
    k_hist<<<(NEDGES + 255) / 256, 256, 0, stream>>>(dst, deg);
    int nb = (NNODES + 255) / 256;
    k_scan1<<<nb, 256, 0, stream>>>(deg, scn, part, NNODES);
    k_scan1<<<1, 256, 0, stream>>>(part, part, dmy, nb);
    k_scan3<<<nb, 256, 0, stream>>>(scn, deg, part, offs, curs, NNODES);
    k_scatter<<<(NEDGES + 255) / 256, 256, 0, stream>>>(dst, src, curs, esrc);

    int gm = (NNODES + 127) / 128;  // 391
    // ---- layer 0: ft = bf16(x @ W0); h0 -> h0bf (bf16) ----
    k_gemm<128, false, false><<<dim3(gm, 2), 256, 0, stream>>>(x, w0t, nullptr,
                                                               nullptr, ft, NNODES, CH);
    k_el_er<4><<<NNODES / 4, 256, 0, stream>>>(ft, al0, ar0, el0, er0);
    k_agg<4, true, false><<<NNODES / 4, 256, 0, stream>>>(ft, el0, er0, offs, deg, esrc,
                                                          nullptr, b0, h0bf, nullptr);
    // ---- layer 1: ft = bf16(h0 @ W1); residual = h0bf; h -> out_h (f32) ----
    k_gemm<128, true, false><<<dim3(gm, 2), 256, 0, stream>>>(h0bf, w1t, nullptr,
                                                              nullptr, ft, NNODES, CH);
    k_el_er<1><<<NNODES / 4, 256, 0, stream>>>(ft, al1, ar1, el1, er1);
    k_agg<1, false, true><<<NNODES / 4, 256, 0, stream>>>(ft, el1, er1, offs, deg, esrc,
                                                          h0bf, b1, nullptr, out_h);
    // ---- classifier: logits(f32) = h @ Wl + bl ----
    k_gemm<64, false, true><<<dim3(gm, 1), 256, 0, stream>>>(out_h, wlt, bl,
                                                             out_logits, nullptr, NNODES, NCLS);
}

// Round 7
// 419.421 us; speedup vs baseline: 1.5334x; 1.0306x over previous
//
#include <hip/hip_runtime.h>
#include <hip/hip_bf16.h>
#include <stdint.h>

#define NNODES 50000
#define NEDGES 800000
#define CH     256
#define NCLS   64

typedef __attribute__((ext_vector_type(8))) short  short8;
typedef __attribute__((ext_vector_type(4))) float  floatx4;

__device__ __forceinline__ float bf2f(unsigned short u) {
    union { unsigned int i; float f; } v; v.i = ((unsigned int)u) << 16; return v.f;
}
__device__ __forceinline__ unsigned short f2bf(float f) {
    union { float f; unsigned int i; } v; v.f = f;
    unsigned int x = v.i;
    return (unsigned short)((x + 0x7fffu + ((x >> 16) & 1u)) >> 16);  // RNE
}

// ---------------- fused setup: zero deg + transpose-convert all 3 weights ----------------
__global__ void k_setup(const float* __restrict__ W0, const float* __restrict__ W1,
                        const float* __restrict__ Wl,
                        unsigned short* __restrict__ w0t, unsigned short* __restrict__ w1t,
                        unsigned short* __restrict__ wlt, int* __restrict__ deg) {
    int i = blockIdx.x * 256 + threadIdx.x;
    if (i < 65536) {
        int r = i >> 8, c = i & 255;
        w0t[c * 256 + r] = f2bf(W0[i]);
    } else if (i < 131072) {
        int j = i - 65536;
        int r = j >> 8, c = j & 255;
        w1t[c * 256 + r] = f2bf(W1[j]);
    } else if (i < 147456) {
        int j = i - 131072;
        int r = j >> 6, c = j & 63;       // Wl is [256,64]
        wlt[c * 256 + r] = f2bf(Wl[j]);
    } else if (i < 147456 + NNODES) {
        deg[i - 147456] = 0;
    }
}

__global__ void k_hist(const int* __restrict__ dst, int* __restrict__ deg) {
    int e = blockIdx.x * 256 + threadIdx.x;
    if (e < NEDGES) {
        int d = dst[e];
        if ((unsigned)d < NNODES) atomicAdd(&deg[d], 1);
    }
}

__global__ void k_scan1(const int* __restrict__ in, int* __restrict__ out,
                        int* __restrict__ part, int n) {
    __shared__ int sm[256];
    int i = blockIdx.x * 256 + threadIdx.x;
    int v = (i < n) ? in[i] : 0;
    sm[threadIdx.x] = v;
    __syncthreads();
    for (int off = 1; off < 256; off <<= 1) {
        int t = (threadIdx.x >= (unsigned)off) ? sm[threadIdx.x - off] : 0;
        __syncthreads();
        sm[threadIdx.x] += t;
        __syncthreads();
    }
    if (i < n) out[i] = sm[threadIdx.x];
    if (threadIdx.x == 255) part[blockIdx.x] = sm[255];
}

__global__ void k_scan3(const int* __restrict__ scn, const int* __restrict__ deg,
                        const int* __restrict__ part, int* __restrict__ offs,
                        int* __restrict__ cursor, int n) {
    int i = blockIdx.x * 256 + threadIdx.x;
    if (i < n) {
        int add = (blockIdx.x > 0) ? part[blockIdx.x - 1] : 0;
        int o = scn[i] - deg[i] + add;
        offs[i] = o; cursor[i] = o;
    }
}

__global__ void k_scatter(const int* __restrict__ dst, const int* __restrict__ src,
                          int* __restrict__ cursor, int* __restrict__ esrc) {
    int e = blockIdx.x * 256 + threadIdx.x;
    if (e < NEDGES) {
        int d = dst[e];
        if ((unsigned)d < NNODES) {
            int p = atomicAdd(&cursor[d], 1);
            if ((unsigned)p < NEDGES) esrc[p] = src[e];
        }
    }
}

// ---------------- GEMM: C[M, N] tile 128(M) x BN(N); A[M,256] f32 or bf16 ----------------
template<int BN, bool ABF16, bool OUTF32>
__global__ __launch_bounds__(256) void k_gemm(const void* __restrict__ Av,
                                              const unsigned short* __restrict__ BT,
                                              const float* __restrict__ bias,
                                              float* __restrict__ Cf,
                                              unsigned short* __restrict__ Cb,
                                              int M, int N) {
    constexpr int BK  = 32;
    constexpr int NT  = BN / 16;
    constexpr int LDA = BK + 8;
    __shared__ unsigned short As[128][LDA];
    __shared__ unsigned short Bs[BN][LDA];
    const int t  = threadIdx.x;
    const int w  = t >> 6, l = t & 63;
    const int lm = l & 15, lk = (l >> 4) * 8;
    const int m0 = blockIdx.x * 128;
    const int n0 = blockIdx.y * BN;
    const float* Af = (const float*)Av;
    const unsigned short* Ab = (const unsigned short*)Av;

    floatx4 acc[2][NT];
#pragma unroll
    for (int mt = 0; mt < 2; ++mt)
#pragma unroll
        for (int nt = 0; nt < NT; ++nt) acc[mt][nt] = (floatx4)0.0f;

    for (int k0 = 0; k0 < 256; k0 += BK) {
        if (ABF16) {
#pragma unroll
            for (int p = 0; p < 2; ++p) {
                int chunk = t + p * 256;
                int r = chunk >> 2, cc = (chunk & 3) * 8;
                int row = m0 + r;
                uint4 val = make_uint4(0, 0, 0, 0);
                if (row < M) val = *(const uint4*)(Ab + (size_t)row * 256 + k0 + cc);
                *(uint4*)&As[r][cc] = val;
            }
        } else {
#pragma unroll
            for (int p = 0; p < 4; ++p) {
                int chunk = t + p * 256;
                int r = chunk >> 3, cc = (chunk & 7) * 4;
                int row = m0 + r;
                float4 v = make_float4(0.f, 0.f, 0.f, 0.f);
                if (row < M) v = *(const float4*)(Af + (size_t)row * 256 + k0 + cc);
                ushort4 o; o.x = f2bf(v.x); o.y = f2bf(v.y); o.z = f2bf(v.z); o.w = f2bf(v.w);
                *(ushort4*)&As[r][cc] = o;
            }
        }
#pragma unroll
        for (int p = 0; p < (BN * 4) / 256; ++p) {
            int chunk = t + p * 256;
            int r = chunk >> 2, cc = (chunk & 3) * 8;
            *(uint4*)&Bs[r][cc] = *(const uint4*)(BT + (size_t)(n0 + r) * 256 + k0 + cc);
        }
        __syncthreads();
        short8 af0 = *(const short8*)&As[w * 32 +      lm][lk];
        short8 af1 = *(const short8*)&As[w * 32 + 16 + lm][lk];
#pragma unroll
        for (int nt = 0; nt < NT; ++nt) {
            short8 bf = *(const short8*)&Bs[nt * 16 + lm][lk];
            acc[0][nt] = __builtin_amdgcn_mfma_f32_16x16x32_bf16(af0, bf, acc[0][nt], 0, 0, 0);
            acc[1][nt] = __builtin_amdgcn_mfma_f32_16x16x32_bf16(af1, bf, acc[1][nt], 0, 0, 0);
        }
        __syncthreads();
    }
#pragma unroll
    for (int mt = 0; mt < 2; ++mt)
#pragma unroll
        for (int j = 0; j < 4; ++j) {
            int row = m0 + w * 32 + mt * 16 + (l >> 4) * 4 + j;
            if (row < M) {
#pragma unroll
                for (int nt = 0; nt < NT; ++nt) {
                    int gcol = n0 + nt * 16 + lm;
                    float v = acc[mt][nt][j];
                    if (bias) v += bias[gcol];
                    if (OUTF32) Cf[(size_t)row * N + gcol] = v;
                    else        Cb[(size_t)row * N + gcol] = f2bf(v);
                }
            }
        }
}

// ---------------- per-node attention logits el/er ----------------
template<int H>
__global__ void k_el_er(const unsigned short* __restrict__ ft,
                        const float* __restrict__ al, const float* __restrict__ ar,
                        float* __restrict__ el, float* __restrict__ er) {
    constexpr int D = CH / H;
    constexpr int G = D / 4;
    int n = blockIdx.x * 4 + (threadIdx.x >> 6);
    int l = threadIdx.x & 63;
    int c = 4 * l;
    int h = c / D;
    ushort4 f = *(const ushort4*)(ft + (size_t)n * CH + c);
    float4 a = *(const float4*)(al + c);
    float4 b = *(const float4*)(ar + c);
    float f0 = bf2f(f.x), f1 = bf2f(f.y), f2 = bf2f(f.z), f3 = bf2f(f.w);
    float sl = f0 * a.x + f1 * a.y + f2 * a.z + f3 * a.w;
    float sr = f0 * b.x + f1 * b.y + f2 * b.z + f3 * b.w;
#pragma unroll
    for (int m = 1; m < G; m <<= 1) {
        sl += __shfl_xor(sl, m, 64);
        sr += __shfl_xor(sr, m, 64);
    }
    if ((l & (G - 1)) == 0) {
        el[n * H + h] = sl;
        er[n * H + h] = sr;
    }
}

// ---------------- fused edge-softmax + aggregation (one wave per dst node) ----------------
// Two-phase: per 64-slot chunk, phase1 computes each edge-head weight ONCE
// (lane = slot x head), parks weight+src in LDS; phase2 is pure gather-FMA.
template<int H, bool ELU, bool RESID>
__global__ __launch_bounds__(256) void k_agg(const unsigned short* __restrict__ ft,
                      const float* __restrict__ el, const float* __restrict__ er,
                      const int* __restrict__ offs, const int* __restrict__ deg,
                      const int* __restrict__ esrc,
                      const unsigned short* __restrict__ resid16,
                      const float* __restrict__ bias,
                      unsigned short* __restrict__ out_bf,
                      float* __restrict__ out_f) {
    constexpr int D = CH / H;
    constexpr int SLOTS = 64 / H;          // edges per chunk: 16 (H=4) or 64 (H=1)
    __shared__ float swgt[4][64];
    __shared__ int   ssrc[4][64];
    int w = threadIdx.x >> 6;
    int n = blockIdx.x * 4 + w;
    int l = threadIdx.x & 63;
    int c = 4 * l;
    int h = c / D;                         // phase-2 head of this lane
    int slot = l / H, head = l & (H - 1);  // phase-1 edge-slot / head of this lane
    float ern1 = er[n * H + head];         // for phase 1
    int st = offs[n], dg = deg[n];
    if (st < 0 || dg < 0 || st > NEDGES || dg > NEDGES - st) dg = 0;
    float a0 = 0.f, a1 = 0.f, a2 = 0.f, a3 = 0.f, ssum = 0.f;

    for (int i = 0; i < dg; i += SLOTS) {
        // ---- phase 1: one lane per (edge,head) computes the weight once ----
        int idx = i + slot;
        int sv = 0; float wv = 0.f;
        if (idx < dg) {
            sv = esrc[st + idx];
            float xv = el[sv * H + head] + ern1;
            xv = (xv > 0.f) ? xv : 0.2f * xv;
            xv = fminf(xv, 60.f);
            wv = __expf(xv);
        }
        swgt[w][slot * H + head] = wv;
        if (head == 0) ssrc[w][slot] = sv;
        // same-wave LDS RAW: hardware lgkmcnt ordering, no barrier needed
        // ---- phase 2: gather ft rows, FMA with broadcast weights ----
        int jmax = dg - i; if (jmax > SLOTS) jmax = SLOTS;
        int j = 0;
        for (; j + 4 <= jmax; j += 4) {
            float w0 = swgt[w][(j + 0) * H + h], w1 = swgt[w][(j + 1) * H + h];
            float w2 = swgt[w][(j + 2) * H + h], w3 = swgt[w][(j + 3) * H + h];
            int s0 = ssrc[w][j + 0], s1 = ssrc[w][j + 1];
            int s2 = ssrc[w][j + 2], s3 = ssrc[w][j + 3];
            ushort4 f0 = *(const ushort4*)(ft + (size_t)s0 * CH + c);
            ushort4 f1 = *(const ushort4*)(ft + (size_t)s1 * CH + c);
            ushort4 f2 = *(const ushort4*)(ft + (size_t)s2 * CH + c);
            ushort4 f3 = *(const ushort4*)(ft + (size_t)s3 * CH + c);
            ssum += (w0 + w1) + (w2 + w3);
            a0 += w0 * bf2f(f0.x) + w1 * bf2f(f1.x) + w2 * bf2f(f2.x) + w3 * bf2f(f3.x);
            a1 += w0 * bf2f(f0.y) + w1 * bf2f(f1.y) + w2 * bf2f(f2.y) + w3 * bf2f(f3.y);
            a2 += w0 * bf2f(f0.z) + w1 * bf2f(f1.z) + w2 * bf2f(f2.z) + w3 * bf2f(f3.z);
            a3 += w0 * bf2f(f0.w) + w1 * bf2f(f1.w) + w2 * bf2f(f2.w) + w3 * bf2f(f3.w);
        }
        for (; j < jmax; ++j) {
            float wj = swgt[w][j * H + h];
            int sj = ssrc[w][j];
            ushort4 f = *(const ushort4*)(ft + (size_t)sj * CH + c);
            ssum += wj;
            a0 += wj * bf2f(f.x); a1 += wj * bf2f(f.y);
            a2 += wj * bf2f(f.z); a3 += wj * bf2f(f.w);
        }
    }
    float inv = (ssum > 1e-30f) ? 1.0f / ssum : 0.0f;
    a0 *= inv; a1 *= inv; a2 *= inv; a3 *= inv;
    if (RESID) {
        ushort4 r = *(const ushort4*)(resid16 + (size_t)n * CH + c);
        a0 += bf2f(r.x); a1 += bf2f(r.y); a2 += bf2f(r.z); a3 += bf2f(r.w);
    }
    {
        float4 b = *(const float4*)(bias + c);
        a0 += b.x; a1 += b.y; a2 += b.z; a3 += b.w;
    }
    if (ELU) {
        a0 = (a0 > 0.f) ? a0 : __expf(a0) - 1.f;
        a1 = (a1 > 0.f) ? a1 : __expf(a1) - 1.f;
        a2 = (a2 > 0.f) ? a2 : __expf(a2) - 1.f;
        a3 = (a3 > 0.f) ? a3 : __expf(a3) - 1.f;
    }
    if (out_bf) {
        ushort4 ov; ov.x = f2bf(a0); ov.y = f2bf(a1); ov.z = f2bf(a2); ov.w = f2bf(a3);
        *(ushort4*)(out_bf + (size_t)n * CH + c) = ov;
    }
    if (out_f) {
        *(float4*)(out_f + (size_t)n * CH + c) = make_float4(a0, a1, a2, a3);
    }
}

// ---------------- launch ----------------

extern "C" void kernel_launch(void* const* d_in, const int* in_sizes, int n_in,
                              void* d_out, int out_size, void* d_ws, size_t ws_size,
                              hipStream_t stream) {
    const float* x   = (const float*)d_in[0];
    const int*   src = (const int*)d_in[1];
    const int*   dst = (const int*)d_in[2];
    const float* W0  = (const float*)d_in[3];
    const float* al0 = (const float*)d_in[4];
    const float* ar0 = (const float*)d_in[5];
    const float* b0  = (const float*)d_in[6];
    const float* W1  = (const float*)d_in[7];
    const float* al1 = (const float*)d_in[8];
    const float* ar1 = (const float*)d_in[9];
    const float* b1  = (const float*)d_in[10];
    const float* Wl  = (const float*)d_in[11];
    const float* bl  = (const float*)d_in[12];

    float* out_logits = (float*)d_out;
    float* out_h      = out_logits + (size_t)NNODES * NCLS;

    // scratch in the logits region (12.8 MB; we use ~6.0 MB), overwritten last
    char* ob = (char*)d_out;
    size_t oo = 0;
    auto oalloc = [&](size_t b) { char* p = ob + oo; oo += (b + 255) & ~(size_t)255; return p; };
    int*   esrc = (int*)oalloc((size_t)NEDGES * 4);
    int*   deg  = (int*)oalloc((size_t)NNODES * 4);
    int*   offs = (int*)oalloc((size_t)NNODES * 4);
    int*   curs = (int*)oalloc((size_t)NNODES * 4);
    int*   scn  = (int*)oalloc((size_t)NNODES * 4);
    float* el0  = (float*)oalloc((size_t)NNODES * 4 * 4);
    float* er0  = (float*)oalloc((size_t)NNODES * 4 * 4);
    float* el1  = (float*)oalloc((size_t)NNODES * 4);
    float* er1  = (float*)oalloc((size_t)NNODES * 4);

    // ws: ft (25.6) + h0bf (25.6) + weights (~0.3) [+ h1bf (25.6) if room]
    char* ws = (char*)d_ws;
    size_t o = 0;
    auto alloc = [&](size_t b) { char* p = ws + o; o += (b + 255) & ~(size_t)255; return p; };
    unsigned short* ft   = (unsigned short*)alloc((size_t)NNODES * CH * 2);
    unsigned short* h0bf = (unsigned short*)alloc((size_t)NNODES * CH * 2);
    unsigned short* w0t  = (unsigned short*)alloc(256 * 256 * 2);
    unsigned short* w1t  = (unsigned short*)alloc(256 * 256 * 2);
    unsigned short* wlt  = (unsigned short*)alloc(64 * 256 * 2);
    int*            part = (int*)alloc(1024);
    int*            dmy  = (int*)alloc(256);
    unsigned short* h1bf = nullptr;
    if (o + (size_t)NNODES * CH * 2 <= ws_size) {
        h1bf = (unsigned short*)alloc((size_t)NNODES * CH * 2);
    }

    // ---- setup + CSR build ----
    k_setup<<<(147456 + NNODES + 255) / 256, 256, 0, stream>>>(W0, W1, Wl, w0t, w1t, wlt, deg);
    k_hist<<<(NEDGES + 255) / 256, 256, 0, stream>>>(dst, deg);
    int nb = (NNODES + 255) / 256;
    k_scan1<<<nb, 256, 0, stream>>>(deg, scn, part, NNODES);
    k_scan1<<<1, 256, 0, stream>>>(part, part, dmy, nb);
    k_scan3<<<nb, 256, 0, stream>>>(scn, deg, part, offs, curs, NNODES);
    k_scatter<<<(NEDGES + 255) / 256, 256, 0, stream>>>(dst, src, curs, esrc);

    int gm = (NNODES + 127) / 128;  // 391
    // ---- layer 0 ----
    k_gemm<128, false, false><<<dim3(gm, 2), 256, 0, stream>>>(x, w0t, nullptr,
                                                               nullptr, ft, NNODES, CH);
    k_el_er<4><<<NNODES / 4, 256, 0, stream>>>(ft, al0, ar0, el0, er0);
    k_agg<4, true, false><<<NNODES / 4, 256, 0, stream>>>(ft, el0, er0, offs, deg, esrc,
                                                          nullptr, b0, h0bf, nullptr);
    // ---- layer 1 ----
    k_gemm<128, true, false><<<dim3(gm, 2), 256, 0, stream>>>(h0bf, w1t, nullptr,
                                                              nullptr, ft, NNODES, CH);
    k_el_er<1><<<NNODES / 4, 256, 0, stream>>>(ft, al1, ar1, el1, er1);
    k_agg<1, false, true><<<NNODES / 4, 256, 0, stream>>>(ft, el1, er1, offs, deg, esrc,
                                                          h0bf, b1, h1bf, out_h);
    // ---- classifier ----
    if (h1bf) {
        k_gemm<64, true, true><<<dim3(gm, 1), 256, 0, stream>>>(h1bf, wlt, bl,
                                                                out_logits, nullptr, NNODES, NCLS);
    } else {
        k_gemm<64, false, true><<<dim3(gm, 1), 256, 0, stream>>>(out_h, wlt, bl,
                                                                 out_logits, nullptr, NNODES, NCLS);
    }
}